// Round 23
// baseline (347.272 us; speedup 1.0000x reference)
//
#include <hip/hip_runtime.h>
#include <hip/hip_bf16.h>

using u16 = unsigned short;
using u32 = unsigned int;
typedef __attribute__((ext_vector_type(8))) short bf16x8;
typedef __attribute__((ext_vector_type(4))) float f32x4;

#define DEVFN __device__ __forceinline__

static constexpr int Sn = 64*64*64;          // 262144 spatial per (b,c)
static constexpr float EPS_ = 1e-5f;

DEVFN float lo2f(u32 u){ union { u32 i; float f; } v; v.i = u << 16; return v.f; }
DEVFN float hi2f(u32 u){ union { u32 i; float f; } v; v.i = u & 0xffff0000u; return v.f; }
DEVFN float b2f(u16 u){ union { u32 i; float f; } v; v.i = ((u32)u) << 16; return v.f; }
DEVFN u16 f2b(float f){
  union { float f; u32 i; } v; v.f = f;
  u32 r = v.i + 0x7fffu + ((v.i >> 16) & 1u);
  return (u16)(r >> 16);
}
DEVFN void unpack8(uint4 v, float* f){
  f[0]=lo2f(v.x); f[1]=hi2f(v.x);
  f[2]=lo2f(v.y); f[3]=hi2f(v.y);
  f[4]=lo2f(v.z); f[5]=hi2f(v.z);
  f[6]=lo2f(v.w); f[7]=hi2f(v.w);
}
DEVFN void unpack4(uint2 v, float* f){
  f[0]=lo2f(v.x); f[1]=hi2f(v.x);
  f[2]=lo2f(v.y); f[3]=hi2f(v.y);
}
DEVFN void load8f(const float* p, float* f){
  float4 a = *reinterpret_cast<const float4*>(p);
  float4 b = *reinterpret_cast<const float4*>(p + 4);
  f[0]=a.x; f[1]=a.y; f[2]=a.z; f[3]=a.w;
  f[4]=b.x; f[5]=b.y; f[6]=b.z; f[7]=b.w;
}

// ------------- stats: partial sums per (b,c, quarter) + bf16 cast of x -------------
__global__ __launch_bounds__(256) void k_stats_partial(
    const float* __restrict__ x, float2* __restrict__ psum, u16* __restrict__ xb){
  int bid = blockIdx.x;            // 768 = 192 bc * 4 chunks
  int bc = bid >> 2, chunk = bid & 3;
  size_t base = (size_t)bc * Sn + (size_t)chunk * (Sn/4);
  const float* p = x + base;
  u16* q = xb + base;
  float s = 0.f, s2 = 0.f;
  int t = threadIdx.x;
  #pragma unroll 4
  for (int k = 0; k < 32; ++k){
    size_t off = (size_t)k*2048 + t*8;
    float f[8]; load8f(p + off, f);
    u16 ob[8];
    #pragma unroll
    for (int j=0;j<8;j++){ s += f[j]; s2 += f[j]*f[j]; ob[j] = f2b(f[j]); }
    *reinterpret_cast<uint4*>(q + off) = *reinterpret_cast<const uint4*>(ob);
  }
  #pragma unroll
  for (int off=32; off; off>>=1){ s += __shfl_down(s, off); s2 += __shfl_down(s2, off); }
  __shared__ float rs[4], rs2[4];
  int wid = t >> 6;
  if ((t & 63) == 0){ rs[wid]=s; rs2[wid]=s2; }
  __syncthreads();
  if (t == 0){
    psum[bid] = make_float2(rs[0]+rs[1]+rs[2]+rs[3], rs2[0]+rs2[1]+rs2[2]+rs2[3]);
  }
}

// ---------- finalize stats; emit LDS-ready [96][104] bf16 weight images ----------
__global__ __launch_bounds__(96) void k_fold(
    const float2* __restrict__ psum,
    const float* __restrict__ gamma, const float* __restrict__ beta,
    const float* __restrict__ in_w, const float* __restrict__ in_b,
    const float* __restrict__ out_w,
    u16* __restrict__ W2pad /* [b][96][104] */,
    u16* __restrict__ W3pad /* [96][104] */,
    float* __restrict__ bias2 /* [b][96] */){
  int blk = blockIdx.x;
  int c = threadIdx.x;        // 0..95
  if (blk < 192){
    int b = blk / 96, o = blk - (blk/96)*96;
    float s=0.f, s2=0.f;
    #pragma unroll
    for (int k=0;k<4;k++){ float2 v = psum[(b*96 + c)*4 + k]; s += v.x; s2 += v.y; }
    float inv = 1.f / (float)Sn;
    float mean = s * inv;
    float var  = s2 * inv - mean*mean;
    float sc = gamma[c] * rsqrtf(var + EPS_);
    float sh = beta[c] - mean * sc;
    float w = in_w[o*96 + c];
    W2pad[(size_t)(b*96 + o)*104 + c] = f2b(w * sc);
    __shared__ float red[96];
    red[c] = w * sh;
    __syncthreads();
    if (c == 0){
      float a = in_b[o];
      for (int i=0;i<96;i++) a += red[i];
      bias2[b*96 + o] = a;
    }
  } else {
    int o = blk - 192;
    W3pad[(size_t)o*104 + c] = f2b(out_w[o*96 + c]);
  }
}

// ---------------- MFMA GEMM (both channel mixes) ----------------
template<int MODE>
__global__ __launch_bounds__(256, 4) void k_gemm(
    const u16*  __restrict__ xb,    // MODE0 src; MODE1 residual
    const u16*  __restrict__ y1,    // MODE1: ws, plane b*48+c
    const u16*  __restrict__ y2,    // MODE1: ws, plane b*48+(c-48)
    const u16*  __restrict__ Wpad,  // [96][104] images
    const float* __restrict__ bias,
    u16* __restrict__ dst16,
    float* __restrict__ dst32){
  __shared__ __attribute__((aligned(16))) u16 lds[18432];  // 36864 B
  u16* Wl = lds;           // [96][104] = 9984 u16 (1248 uint4)
  u16* X  = lds + 9984;    // [64][132] = 8448 u16
  const int t  = threadIdx.x;
  const int b  = blockIdx.x >> 12;
  const int s0 = (blockIdx.x & 4095) << 6;     // 64-s tile

  {
    const uint4* wsrc = reinterpret_cast<const uint4*>(Wpad + (MODE==0 ? (size_t)b*9984 : 0));
    uint4* wdst = reinterpret_cast<uint4*>(lds);
    #pragma unroll
    for (int i=0;i<5;i++){ int idx = i*256 + t; if (idx < 1248) wdst[idx] = wsrc[idx]; }
  }

  #pragma unroll
  for (int it=0; it<2; ++it){
    int task = it*256 + t;                // 384 tasks = 32 s-pairs x 12 c-octets
    if (task < 384){
      int sp = task & 31, cblk = task >> 5;
      int s = sp*2;
      u16 rA[8], rB[8];
      #pragma unroll
      for (int j=0;j<8;j++){
        int c = cblk*8 + j;
        const u16* src;
        if (MODE==0)      src = xb + ((size_t)(b*96 + c))*Sn;
        else if (c < 48)  src = y1 + ((size_t)(b*48 + c))*Sn;
        else              src = y2 + ((size_t)(b*48 + (c-48)))*Sn;
        u32 v = *reinterpret_cast<const u32*>(src + s0 + s);
        rA[j] = (u16)v; rB[j] = (u16)(v >> 16);
      }
      *reinterpret_cast<uint4*>(&X[(size_t)s*132 + cblk*8]) = *reinterpret_cast<const uint4*>(rA);
      *reinterpret_cast<uint2*>(&X[(size_t)(s+1)*132 + cblk*8])     = *reinterpret_cast<const uint2*>(&rB[0]);
      *reinterpret_cast<uint2*>(&X[(size_t)(s+1)*132 + cblk*8 + 4]) = *reinterpret_cast<const uint2*>(&rB[4]);
    }
  }
  __syncthreads();

  const int w  = t >> 6;
  const int l  = t & 63;
  const int lc = l & 15, lr = l >> 4;

  f32x4 acc[6];
  #pragma unroll
  for (int m=0;m<6;m++)
    #pragma unroll
    for (int r=0;r<4;r++) acc[m][r] = 0.f;

  #pragma unroll
  for (int kk=0; kk<3; ++kk){
    const int kb = kk*4 + lr;
    bf16x8 xv;
    {
      const u16* px = &X[(size_t)(w*16 + lc)*132 + kb*8];
      uint2 p0 = *reinterpret_cast<const uint2*>(px);
      uint2 p1 = *reinterpret_cast<const uint2*>(px + 4);
      union { uint4 u; bf16x8 v; } cv;
      cv.u = make_uint4(p0.x, p0.y, p1.x, p1.y);
      xv = cv.v;
    }
    #pragma unroll
    for (int m=0;m<6;m++){
      bf16x8 a = *reinterpret_cast<const bf16x8*>(&Wl[(size_t)(16*m + lc)*104 + kb*8]);
      acc[m] = __builtin_amdgcn_mfma_f32_16x16x32_bf16(a, xv, acc[m], 0, 0, 0);
    }
  }
  __syncthreads();

  if (MODE==0){
    u16* eps = lds;              // [96][72]
    #pragma unroll
    for (int m=0;m<6;m++){
      #pragma unroll
      for (int r=0;r<4;r++){
        int o = 16*m + lr*4 + r;
        eps[(size_t)o*72 + w*16 + lc] = f2b(acc[m][r] + bias[b*96 + o]);
      }
    }
    __syncthreads();
    #pragma unroll
    for (int i=0;i<3;i++){
      int idx = i*256 + t;
      int o = idx >> 3, qq = idx & 7;
      *reinterpret_cast<uint4*>(dst16 + ((size_t)(b*96 + o))*Sn + s0 + qq*8) =
          *reinterpret_cast<const uint4*>(&eps[(size_t)o*72 + qq*8]);
    }
  } else {
    float* eps = reinterpret_cast<float*>(lds);   // [96][68] f32
    #pragma unroll
    for (int m=0;m<6;m++){
      #pragma unroll
      for (int r=0;r<4;r++){
        int o = 16*m + lr*4 + r;
        eps[(size_t)o*68 + w*16 + lc] = acc[m][r] + bias[o];
      }
    }
    __syncthreads();
    #pragma unroll
    for (int i=0;i<6;i++){
      int idx = i*256 + t;
      int o = idx >> 4, qq = idx & 15;
      size_t off = ((size_t)(b*96 + o))*Sn + s0 + qq*4;
      float4 v  = *reinterpret_cast<const float4*>(&eps[(size_t)o*68 + qq*4]);
      uint2 rv = *reinterpret_cast<const uint2*>(xb + off);
      float rf[4]; unpack4(rv, rf);
      v.x += rf[0]; v.y += rf[1]; v.z += rf[2]; v.w += rf[3];
      *reinterpret_cast<float4*>(dst32 + off) = v;
    }
  }
}

// -------- depthwise 3x3x3 conv, 4 d-slices x 8 outputs/thread --------
// Thread computes outputs at d0..d3: 6 input slices for 32 outputs.
// Each loaded row feeds up to 3 accumulators with compile-time weight banks.
#define DW_TAP4(SL, ROF, OKR, F0, OK0, KB0, F1, KB1, F2, KB2, F3, OK3, KB3) { \
    float m_[8]; \
    unpack8(*reinterpret_cast<const uint4*>((SL) + (ROF)), m_); \
    float rl_ = __shfl_up(m_[7], 1); \
    float rr_ = __shfl_down(m_[0], 1); \
    if ((t & 7) == 0) rl_ = 0.f; \
    if ((t & 7) == 7) rr_ = 0.f; \
    if (F0){ \
      float wa_ = ((OK0) && (OKR)) ? wf[(KB0)+0] : 0.f; \
      float wb_ = ((OK0) && (OKR)) ? wf[(KB0)+1] : 0.f; \
      float wc_ = ((OK0) && (OKR)) ? wf[(KB0)+2] : 0.f; \
      _Pragma("unroll") \
      for (int j=0;j<8;j++){ \
        float L_ = (j==0) ? rl_ : m_[j-1]; \
        float R_ = (j==7) ? rr_ : m_[j+1]; \
        acc0[j] = fmaf(wa_, L_, fmaf(wb_, m_[j], fmaf(wc_, R_, acc0[j]))); \
      } \
    } \
    if (F1){ \
      float wa_ = (OKR) ? wf[(KB1)+0] : 0.f; \
      float wb_ = (OKR) ? wf[(KB1)+1] : 0.f; \
      float wc_ = (OKR) ? wf[(KB1)+2] : 0.f; \
      _Pragma("unroll") \
      for (int j=0;j<8;j++){ \
        float L_ = (j==0) ? rl_ : m_[j-1]; \
        float R_ = (j==7) ? rr_ : m_[j+1]; \
        acc1[j] = fmaf(wa_, L_, fmaf(wb_, m_[j], fmaf(wc_, R_, acc1[j]))); \
      } \
    } \
    if (F2){ \
      float wa_ = (OKR) ? wf[(KB2)+0] : 0.f; \
      float wb_ = (OKR) ? wf[(KB2)+1] : 0.f; \
      float wc_ = (OKR) ? wf[(KB2)+2] : 0.f; \
      _Pragma("unroll") \
      for (int j=0;j<8;j++){ \
        float L_ = (j==0) ? rl_ : m_[j-1]; \
        float R_ = (j==7) ? rr_ : m_[j+1]; \
        acc2[j] = fmaf(wa_, L_, fmaf(wb_, m_[j], fmaf(wc_, R_, acc2[j]))); \
      } \
    } \
    if (F3){ \
      float wa_ = ((OK3) && (OKR)) ? wf[(KB3)+0] : 0.f; \
      float wb_ = ((OK3) && (OKR)) ? wf[(KB3)+1] : 0.f; \
      float wc_ = ((OK3) && (OKR)) ? wf[(KB3)+2] : 0.f; \
      _Pragma("unroll") \
      for (int j=0;j<8;j++){ \
        float L_ = (j==0) ? rl_ : m_[j-1]; \
        float R_ = (j==7) ? rr_ : m_[j+1]; \
        acc3[j] = fmaf(wa_, L_, fmaf(wb_, m_[j], fmaf(wc_, R_, acc3[j]))); \
      } \
    } \
  }

template<int SILU, int MERGED>
__global__ __launch_bounds__(256) void k_dws4(
    const u16* __restrict__ src, int sCPB, int sCOff,
    u16* __restrict__ dst, int dCPB, int dCOff,
    u16* __restrict__ dst2,
    const float* __restrict__ wtsA, const float* __restrict__ biasA,
    const float* __restrict__ wtsB, const float* __restrict__ biasB){
  int hw = blockIdx.x;                  // XCD-chunked swizzle
  int nchunk = MERGED ? 768 : 384;      // blocks/8
  int id = (hw & 7)*nchunk + (hw >> 3);
  int CC = MERGED ? 96 : 48;
  int half = id & 1;
  int dq = (id >> 1) & 15;
  int cc = (id >> 5) % CC;
  int b  = id / (CC*32);
  int d0 = dq*4;
  bool sym = MERGED && (cc >= 48);
  int c = sym ? (cc - 48) : cc;         // explicit: 48 is not a power of two
  const float* wts  = sym ? wtsB  : wtsA;
  const float* bias = sym ? biasB : biasA;
  const int t = threadIdx.x;
  int h = half*32 + (t >> 3), w0 = (t & 7) * 8;

  float wf[27];
  #pragma unroll
  for (int k=0;k<27;k++) wf[k] = wts[c*27 + k];   // block-uniform -> SGPR

  float acc0[8], acc1[8], acc2[8], acc3[8];
  float bv = bias[c];
  #pragma unroll
  for (int j=0;j<8;j++){ acc0[j]=bv; acc1[j]=bv; acc2[j]=bv; acc3[j]=bv; }

  const u16* plane = src + ((size_t)(b*sCPB + sCOff + cc)) * Sn;
  const bool dokm = (d0 > 0), dokp = (d0 + 3 < 63);
  const u16* sA = plane + (dokm ? (d0-1) : 0 )*4096;   // acc0 k=0
  const u16* sB = plane + (d0  )*4096;                 // acc0 k=1, acc1 k=0
  const u16* sC = plane + (d0+1)*4096;                 // acc0 k=2, acc1 k=1, acc2 k=0
  const u16* sD = plane + (d0+2)*4096;                 // acc1 k=2, acc2 k=1, acc3 k=0
  const u16* sE = plane + (d0+3)*4096;                 // acc2 k=2, acc3 k=1
  const u16* sF = plane + (dokp ? (d0+4) : 63)*4096;   // acc3 k=2
  const bool okm = (h > 0), okp = (h < 63);
  const int rofm = (okm ? (h-1) : 0 )*64 + w0;
  const int rof0 = h*64 + w0;
  const int rofp = (okp ? (h+1) : 63)*64 + w0;

  //         SL  ROF   OKR    F0 OK0  KB0  F1 KB1  F2 KB2  F3 OK3  KB3
  DW_TAP4(sA, rofm, okm,  1, dokm, 0,  0, 0,  0, 0,  0, true, 0)
  DW_TAP4(sA, rof0, true, 1, dokm, 3,  0, 0,  0, 0,  0, true, 0)
  DW_TAP4(sA, rofp, okp,  1, dokm, 6,  0, 0,  0, 0,  0, true, 0)
  DW_TAP4(sB, rofm, okm,  1, true, 9,  1, 0,  0, 0,  0, true, 0)
  DW_TAP4(sB, rof0, true, 1, true, 12, 1, 3,  0, 0,  0, true, 0)
  DW_TAP4(sB, rofp, okp,  1, true, 15, 1, 6,  0, 0,  0, true, 0)
  DW_TAP4(sC, rofm, okm,  1, true, 18, 1, 9,  1, 0,  0, true, 0)
  DW_TAP4(sC, rof0, true, 1, true, 21, 1, 12, 1, 3,  0, true, 0)
  DW_TAP4(sC, rofp, okp,  1, true, 24, 1, 15, 1, 6,  0, true, 0)
  DW_TAP4(sD, rofm, okm,  0, true, 0,  1, 18, 1, 9,  1, true, 0)
  DW_TAP4(sD, rof0, true, 0, true, 0,  1, 21, 1, 12, 1, true, 3)
  DW_TAP4(sD, rofp, okp,  0, true, 0,  1, 24, 1, 15, 1, true, 6)
  DW_TAP4(sE, rofm, okm,  0, true, 0,  0, 0,  1, 18, 1, true, 9)
  DW_TAP4(sE, rof0, true, 0, true, 0,  0, 0,  1, 21, 1, true, 12)
  DW_TAP4(sE, rofp, okp,  0, true, 0,  0, 0,  1, 24, 1, true, 15)
  DW_TAP4(sF, rofm, okm,  0, true, 0,  0, 0,  0, 0,  1, dokp, 18)
  DW_TAP4(sF, rof0, true, 0, true, 0,  0, 0,  0, 0,  1, dokp, 21)
  DW_TAP4(sF, rofp, okp,  0, true, 0,  0, 0,  0, 0,  1, dokp, 24)

  u16* base;
  if (MERGED && sym) base = dst2 + ((size_t)(b*48 + c)) * Sn;
  else               base = dst  + ((size_t)(b*dCPB + dCOff + c)) * Sn;
  float* accs[4] = {acc0, acc1, acc2, acc3};
  #pragma unroll
  for (int dd=0; dd<4; ++dd){
    u16 ob[8];
    #pragma unroll
    for (int j=0;j<8;j++){
      float v = accs[dd][j];
      if (SILU) v = v / (1.f + __expf(-v));
      ob[j] = f2b(v);
    }
    *reinterpret_cast<uint4*>(base + (d0+dd)*4096 + h*64 + w0) = *reinterpret_cast<const uint4*>(ob);
  }
}

extern "C" void kernel_launch(void* const* d_in, const int* in_sizes, int n_in,
                              void* d_out, int out_size, void* d_ws, size_t ws_size,
                              hipStream_t stream){
  const float* x      = (const float*)d_in[0];
  const float* gamma  = (const float*)d_in[1];
  const float* beta   = (const float*)d_in[2];
  const float* in_w   = (const float*)d_in[3];
  const float* in_b   = (const float*)d_in[4];
  const float* ssm_w  = (const float*)d_in[5];
  const float* ssm_b  = (const float*)d_in[6];
  const float* mam_w  = (const float*)d_in[7];
  const float* mam_b  = (const float*)d_in[8];
  const float* sym_w  = (const float*)d_in[9];
  const float* sym_b  = (const float*)d_in[10];
  const float* out_w  = (const float*)d_in[11];
  const float* out_b  = (const float*)d_in[12];
  float* out = (float*)d_out;

  // d_out = 384 u16-planes, scratch only BEFORE gemm_out:
  //   xp bf16: planes 0..191 ; t1 bf16: planes 192..239 (b0) / 288..335 (b1)
  u16* du16 = (u16*)d_out;

  // ws layout: y2, y1 each [2][48][Sn] bf16 = 50,331,648 B; xb [2][96][Sn] = 100,663,296 B
  char* ws = (char*)d_ws;
  u16*    y2    = (u16*)ws;                                     // [0, 50331648)
  u16*    y1    = (u16*)(ws + 50331648);                        // [50331648, 100663296)
  u16*    xb    = (u16*)(ws + 100663296);                       // [100663296, 201326592)
  float2* psum  = (float2*)(ws + 201326592);                    // 6,144 B
  u16*    W2pad = (u16*)(ws + 201326592 + 6144);                // 39,936 B
  u16*    W3pad = (u16*)(ws + 201326592 + 6144 + 39936);        // 19,968 B
  float*  bias2 = (float*)(ws + 201326592 + 6144 + 39936 + 19968); // 768 B

  // 1) norm stats + bf16 cast of x
  k_stats_partial<<<768, 256, 0, stream>>>(x, psum, xb);
  // 2) finalize + fold norm into in-proj (parallel); emit weight images
  k_fold<<<288, 96, 0, stream>>>(psum, gamma, beta, in_w, in_b, out_w, W2pad, W3pad, bias2);
  // 3) xp = W2*xb + bias2  (MFMA, bf16 into d_out planes 0..191)
  k_gemm<0><<<8192, 256, 0, stream>>>(xb, nullptr, nullptr, W2pad, bias2, du16, nullptr);
  // 4) merged: t1 = silu(dw_ssm(xp[:, :48])) -> planes 192.. ; y2 = silu(dw_sym(xp[:, 48:])) -> ws
  k_dws4<1,1><<<6144, 256, 0, stream>>>(du16, 96, 0, du16, 96, 192, y2, ssm_w, ssm_b, sym_w, sym_b);
  // 5) y1 = dw_mamba(t1) -> ws
  k_dws4<0,0><<<3072, 256, 0, stream>>>(du16, 96, 192, y1, 48, 0, nullptr, mam_w, mam_b, nullptr, nullptr);
  // 6) out = out_w * [y1; y2] + out_b + xb  (MFMA, fp32 into d_out; reads only ws)
  k_gemm<1><<<8192, 256, 0, stream>>>(xb, y1, y2, W3pad, out_b, nullptr, out);
}

// Round 24
// 321.083 us; speedup vs baseline: 1.0816x; 1.0816x over previous
//
#include <hip/hip_runtime.h>
#include <hip/hip_bf16.h>

using u16 = unsigned short;
using u32 = unsigned int;
typedef __attribute__((ext_vector_type(8))) short bf16x8;
typedef __attribute__((ext_vector_type(4))) float f32x4;

#define DEVFN __device__ __forceinline__

static constexpr int Sn = 64*64*64;          // 262144 spatial per (b,c)
static constexpr float EPS_ = 1e-5f;

DEVFN float lo2f(u32 u){ union { u32 i; float f; } v; v.i = u << 16; return v.f; }
DEVFN float hi2f(u32 u){ union { u32 i; float f; } v; v.i = u & 0xffff0000u; return v.f; }
DEVFN float b2f(u16 u){ union { u32 i; float f; } v; v.i = ((u32)u) << 16; return v.f; }
DEVFN u16 f2b(float f){
  union { float f; u32 i; } v; v.f = f;
  u32 r = v.i + 0x7fffu + ((v.i >> 16) & 1u);
  return (u16)(r >> 16);
}
DEVFN void unpack8(uint4 v, float* f){
  f[0]=lo2f(v.x); f[1]=hi2f(v.x);
  f[2]=lo2f(v.y); f[3]=hi2f(v.y);
  f[4]=lo2f(v.z); f[5]=hi2f(v.z);
  f[6]=lo2f(v.w); f[7]=hi2f(v.w);
}
DEVFN void unpack4(uint2 v, float* f){
  f[0]=lo2f(v.x); f[1]=hi2f(v.x);
  f[2]=lo2f(v.y); f[3]=hi2f(v.y);
}
DEVFN void load8f(const float* p, float* f){
  float4 a = *reinterpret_cast<const float4*>(p);
  float4 b = *reinterpret_cast<const float4*>(p + 4);
  f[0]=a.x; f[1]=a.y; f[2]=a.z; f[3]=a.w;
  f[4]=b.x; f[5]=b.y; f[6]=b.z; f[7]=b.w;
}

// ------------- stats: partial sums per (b,c, quarter) + bf16 cast of x -------------
__global__ __launch_bounds__(256) void k_stats_partial(
    const float* __restrict__ x, float2* __restrict__ psum, u16* __restrict__ xb){
  int bid = blockIdx.x;            // 768 = 192 bc * 4 chunks
  int bc = bid >> 2, chunk = bid & 3;
  size_t base = (size_t)bc * Sn + (size_t)chunk * (Sn/4);
  const float* p = x + base;
  u16* q = xb + base;
  float s = 0.f, s2 = 0.f;
  int t = threadIdx.x;
  #pragma unroll 4
  for (int k = 0; k < 32; ++k){
    size_t off = (size_t)k*2048 + t*8;
    float f[8]; load8f(p + off, f);
    u16 ob[8];
    #pragma unroll
    for (int j=0;j<8;j++){ s += f[j]; s2 += f[j]*f[j]; ob[j] = f2b(f[j]); }
    *reinterpret_cast<uint4*>(q + off) = *reinterpret_cast<const uint4*>(ob);
  }
  #pragma unroll
  for (int off=32; off; off>>=1){ s += __shfl_down(s, off); s2 += __shfl_down(s2, off); }
  __shared__ float rs[4], rs2[4];
  int wid = t >> 6;
  if ((t & 63) == 0){ rs[wid]=s; rs2[wid]=s2; }
  __syncthreads();
  if (t == 0){
    psum[bid] = make_float2(rs[0]+rs[1]+rs[2]+rs[3], rs2[0]+rs2[1]+rs2[2]+rs2[3]);
  }
}

// ---------- finalize stats; emit LDS-ready [96][104] bf16 weight images ----------
__global__ __launch_bounds__(96) void k_fold(
    const float2* __restrict__ psum,
    const float* __restrict__ gamma, const float* __restrict__ beta,
    const float* __restrict__ in_w, const float* __restrict__ in_b,
    const float* __restrict__ out_w,
    u16* __restrict__ W2pad /* [b][96][104] */,
    u16* __restrict__ W3pad /* [96][104] */,
    float* __restrict__ bias2 /* [b][96] */){
  int blk = blockIdx.x;
  int c = threadIdx.x;        // 0..95
  if (blk < 192){
    int b = blk / 96, o = blk - (blk/96)*96;
    float s=0.f, s2=0.f;
    #pragma unroll
    for (int k=0;k<4;k++){ float2 v = psum[(b*96 + c)*4 + k]; s += v.x; s2 += v.y; }
    float inv = 1.f / (float)Sn;
    float mean = s * inv;
    float var  = s2 * inv - mean*mean;
    float sc = gamma[c] * rsqrtf(var + EPS_);
    float sh = beta[c] - mean * sc;
    float w = in_w[o*96 + c];
    W2pad[(size_t)(b*96 + o)*104 + c] = f2b(w * sc);
    __shared__ float red[96];
    red[c] = w * sh;
    __syncthreads();
    if (c == 0){
      float a = in_b[o];
      for (int i=0;i<96;i++) a += red[i];
      bias2[b*96 + o] = a;
    }
  } else {
    int o = blk - 192;
    W3pad[(size_t)o*104 + c] = f2b(out_w[o*96 + c]);
  }
}

// ---------------- MFMA GEMM (both channel mixes) ----------------
template<int MODE>
__global__ __launch_bounds__(256, 4) void k_gemm(
    const u16*  __restrict__ xb,    // MODE0 src; MODE1 residual
    const u16*  __restrict__ y1,    // MODE1: ws, plane b*48+c
    const u16*  __restrict__ y2,    // MODE1: ws, plane b*48+(c-48)
    const u16*  __restrict__ Wpad,  // [96][104] images
    const float* __restrict__ bias,
    u16* __restrict__ dst16,
    float* __restrict__ dst32){
  __shared__ __attribute__((aligned(16))) u16 lds[18432];  // 36864 B
  u16* Wl = lds;           // [96][104] = 9984 u16 (1248 uint4)
  u16* X  = lds + 9984;    // [64][132] = 8448 u16
  const int t  = threadIdx.x;
  const int b  = blockIdx.x >> 12;
  const int s0 = (blockIdx.x & 4095) << 6;     // 64-s tile

  {
    const uint4* wsrc = reinterpret_cast<const uint4*>(Wpad + (MODE==0 ? (size_t)b*9984 : 0));
    uint4* wdst = reinterpret_cast<uint4*>(lds);
    #pragma unroll
    for (int i=0;i<5;i++){ int idx = i*256 + t; if (idx < 1248) wdst[idx] = wsrc[idx]; }
  }

  #pragma unroll
  for (int it=0; it<2; ++it){
    int task = it*256 + t;                // 384 tasks = 32 s-pairs x 12 c-octets
    if (task < 384){
      int sp = task & 31, cblk = task >> 5;
      int s = sp*2;
      u16 rA[8], rB[8];
      #pragma unroll
      for (int j=0;j<8;j++){
        int c = cblk*8 + j;
        const u16* src;
        if (MODE==0)      src = xb + ((size_t)(b*96 + c))*Sn;
        else if (c < 48)  src = y1 + ((size_t)(b*48 + c))*Sn;
        else              src = y2 + ((size_t)(b*48 + (c-48)))*Sn;
        u32 v = *reinterpret_cast<const u32*>(src + s0 + s);
        rA[j] = (u16)v; rB[j] = (u16)(v >> 16);
      }
      *reinterpret_cast<uint4*>(&X[(size_t)s*132 + cblk*8]) = *reinterpret_cast<const uint4*>(rA);
      *reinterpret_cast<uint2*>(&X[(size_t)(s+1)*132 + cblk*8])     = *reinterpret_cast<const uint2*>(&rB[0]);
      *reinterpret_cast<uint2*>(&X[(size_t)(s+1)*132 + cblk*8 + 4]) = *reinterpret_cast<const uint2*>(&rB[4]);
    }
  }
  __syncthreads();

  const int w  = t >> 6;
  const int l  = t & 63;
  const int lc = l & 15, lr = l >> 4;

  f32x4 acc[6];
  #pragma unroll
  for (int m=0;m<6;m++)
    #pragma unroll
    for (int r=0;r<4;r++) acc[m][r] = 0.f;

  #pragma unroll
  for (int kk=0; kk<3; ++kk){
    const int kb = kk*4 + lr;
    bf16x8 xv;
    {
      const u16* px = &X[(size_t)(w*16 + lc)*132 + kb*8];
      uint2 p0 = *reinterpret_cast<const uint2*>(px);
      uint2 p1 = *reinterpret_cast<const uint2*>(px + 4);
      union { uint4 u; bf16x8 v; } cv;
      cv.u = make_uint4(p0.x, p0.y, p1.x, p1.y);
      xv = cv.v;
    }
    #pragma unroll
    for (int m=0;m<6;m++){
      bf16x8 a = *reinterpret_cast<const bf16x8*>(&Wl[(size_t)(16*m + lc)*104 + kb*8]);
      acc[m] = __builtin_amdgcn_mfma_f32_16x16x32_bf16(a, xv, acc[m], 0, 0, 0);
    }
  }
  __syncthreads();

  if (MODE==0){
    u16* eps = lds;              // [96][72]
    #pragma unroll
    for (int m=0;m<6;m++){
      #pragma unroll
      for (int r=0;r<4;r++){
        int o = 16*m + lr*4 + r;
        eps[(size_t)o*72 + w*16 + lc] = f2b(acc[m][r] + bias[b*96 + o]);
      }
    }
    __syncthreads();
    #pragma unroll
    for (int i=0;i<3;i++){
      int idx = i*256 + t;
      int o = idx >> 3, qq = idx & 7;
      *reinterpret_cast<uint4*>(dst16 + ((size_t)(b*96 + o))*Sn + s0 + qq*8) =
          *reinterpret_cast<const uint4*>(&eps[(size_t)o*72 + qq*8]);
    }
  } else {
    float* eps = reinterpret_cast<float*>(lds);   // [96][68] f32
    #pragma unroll
    for (int m=0;m<6;m++){
      #pragma unroll
      for (int r=0;r<4;r++){
        int o = 16*m + lr*4 + r;
        eps[(size_t)o*68 + w*16 + lc] = acc[m][r] + bias[o];
      }
    }
    __syncthreads();
    #pragma unroll
    for (int i=0;i<6;i++){
      int idx = i*256 + t;
      int o = idx >> 4, qq = idx & 15;
      size_t off = ((size_t)(b*96 + o))*Sn + s0 + qq*4;
      float4 v  = *reinterpret_cast<const float4*>(&eps[(size_t)o*68 + qq*4]);
      uint2 rv = *reinterpret_cast<const uint2*>(xb + off);
      float rf[4]; unpack4(rv, rf);
      v.x += rf[0]; v.y += rf[1]; v.z += rf[2]; v.w += rf[3];
      *reinterpret_cast<float4*>(dst32 + off) = v;
    }
  }
}

// -------- depthwise 3x3x3 conv, 2 d-slices x 8 outputs/thread --------
// Each thread computes outputs at (d0, d1=d0+1): 4 input slices instead of 6,
// rows loaded once feed both accumulators with different compile-time weight banks.
#define DW_TAP2(SL, ROF, OKR, F0, OK0, KB0, F1, OK1, KB1) { \
    float m_[8]; \
    unpack8(*reinterpret_cast<const uint4*>((SL) + (ROF)), m_); \
    float rl_ = __shfl_up(m_[7], 1); \
    float rr_ = __shfl_down(m_[0], 1); \
    if ((t & 7) == 0) rl_ = 0.f; \
    if ((t & 7) == 7) rr_ = 0.f; \
    if (F0){ \
      float wa_ = ((OK0) && (OKR)) ? wf[(KB0)+0] : 0.f; \
      float wb_ = ((OK0) && (OKR)) ? wf[(KB0)+1] : 0.f; \
      float wc_ = ((OK0) && (OKR)) ? wf[(KB0)+2] : 0.f; \
      _Pragma("unroll") \
      for (int j=0;j<8;j++){ \
        float L_ = (j==0) ? rl_ : m_[j-1]; \
        float R_ = (j==7) ? rr_ : m_[j+1]; \
        acc0[j] = fmaf(wa_, L_, fmaf(wb_, m_[j], fmaf(wc_, R_, acc0[j]))); \
      } \
    } \
    if (F1){ \
      float wa_ = ((OK1) && (OKR)) ? wf[(KB1)+0] : 0.f; \
      float wb_ = ((OK1) && (OKR)) ? wf[(KB1)+1] : 0.f; \
      float wc_ = ((OK1) && (OKR)) ? wf[(KB1)+2] : 0.f; \
      _Pragma("unroll") \
      for (int j=0;j<8;j++){ \
        float L_ = (j==0) ? rl_ : m_[j-1]; \
        float R_ = (j==7) ? rr_ : m_[j+1]; \
        acc1[j] = fmaf(wa_, L_, fmaf(wb_, m_[j], fmaf(wc_, R_, acc1[j]))); \
      } \
    } \
  }

template<int SILU, int MERGED>
__global__ __launch_bounds__(256) void k_dws2(
    const u16* __restrict__ src, int sCPB, int sCOff,
    u16* __restrict__ dst, int dCPB, int dCOff,
    u16* __restrict__ dst2,
    const float* __restrict__ wtsA, const float* __restrict__ biasA,
    const float* __restrict__ wtsB, const float* __restrict__ biasB){
  int hw = blockIdx.x;                  // XCD-chunked swizzle
  int nchunk = MERGED ? 1536 : 768;     // blocks/8
  int id = (hw & 7)*nchunk + (hw >> 3);
  int CC = MERGED ? 96 : 48;
  int half = id & 1;
  int dp = (id >> 1) & 31;
  int cc = (id >> 6) % CC;
  int b  = id / (CC*64);
  int d0 = dp*2, d1 = d0 + 1;
  bool sym = MERGED && (cc >= 48);
  int c = sym ? (cc - 48) : cc;         // explicit: 48 is not a power of two
  const float* wts  = sym ? wtsB  : wtsA;
  const float* bias = sym ? biasB : biasA;
  const int t = threadIdx.x;
  int h = half*32 + (t >> 3), w0 = (t & 7) * 8;

  float wf[27];
  #pragma unroll
  for (int k=0;k<27;k++) wf[k] = wts[c*27 + k];   // block-uniform -> SGPR

  float acc0[8], acc1[8];
  float bv = bias[c];
  #pragma unroll
  for (int j=0;j<8;j++){ acc0[j] = bv; acc1[j] = bv; }

  const u16* plane = src + ((size_t)(b*sCPB + sCOff + cc)) * Sn;
  const bool dok0 = (d0 > 0), dok3 = (d1 < 63);
  const u16* sA = plane + (dok0 ? (d0-1) : 0 )*4096;   // d0-1 (acc0 k=0)
  const u16* sB = plane + d0*4096;                     // d0   (acc0 k=1, acc1 k=0)
  const u16* sC = plane + d1*4096;                     // d1   (acc0 k=2, acc1 k=1)
  const u16* sD = plane + (dok3 ? (d1+1) : 63)*4096;   // d1+1 (acc1 k=2)
  const bool okm = (h > 0), okp = (h < 63);
  const int rofm = (okm ? (h-1) : 0 )*64 + w0;
  const int rof0 = h*64 + w0;
  const int rofp = (okp ? (h+1) : 63)*64 + w0;

  DW_TAP2(sA, rofm, okm,  1, dok0, 0,  0, true, 0)
  DW_TAP2(sA, rof0, true, 1, dok0, 3,  0, true, 0)
  DW_TAP2(sA, rofp, okp,  1, dok0, 6,  0, true, 0)
  DW_TAP2(sB, rofm, okm,  1, true, 9,  1, true, 0)
  DW_TAP2(sB, rof0, true, 1, true, 12, 1, true, 3)
  DW_TAP2(sB, rofp, okp,  1, true, 15, 1, true, 6)
  DW_TAP2(sC, rofm, okm,  1, true, 18, 1, true, 9)
  DW_TAP2(sC, rof0, true, 1, true, 21, 1, true, 12)
  DW_TAP2(sC, rofp, okp,  1, true, 24, 1, true, 15)
  DW_TAP2(sD, rofm, okm,  0, true, 0,  1, dok3, 18)
  DW_TAP2(sD, rof0, true, 0, true, 0,  1, dok3, 21)
  DW_TAP2(sD, rofp, okp,  0, true, 0,  1, dok3, 24)

  u16 ob0[8], ob1[8];
  #pragma unroll
  for (int j=0;j<8;j++){
    float v0 = acc0[j], v1 = acc1[j];
    if (SILU){ v0 = v0 / (1.f + __expf(-v0)); v1 = v1 / (1.f + __expf(-v1)); }
    ob0[j] = f2b(v0); ob1[j] = f2b(v1);
  }
  u16* base;
  if (MERGED && sym) base = dst2 + ((size_t)(b*48 + c)) * Sn;
  else               base = dst  + ((size_t)(b*dCPB + dCOff + c)) * Sn;
  *reinterpret_cast<uint4*>(base + d0*4096 + h*64 + w0) = *reinterpret_cast<const uint4*>(ob0);
  *reinterpret_cast<uint4*>(base + d1*4096 + h*64 + w0) = *reinterpret_cast<const uint4*>(ob1);
}

extern "C" void kernel_launch(void* const* d_in, const int* in_sizes, int n_in,
                              void* d_out, int out_size, void* d_ws, size_t ws_size,
                              hipStream_t stream){
  const float* x      = (const float*)d_in[0];
  const float* gamma  = (const float*)d_in[1];
  const float* beta   = (const float*)d_in[2];
  const float* in_w   = (const float*)d_in[3];
  const float* in_b   = (const float*)d_in[4];
  const float* ssm_w  = (const float*)d_in[5];
  const float* ssm_b  = (const float*)d_in[6];
  const float* mam_w  = (const float*)d_in[7];
  const float* mam_b  = (const float*)d_in[8];
  const float* sym_w  = (const float*)d_in[9];
  const float* sym_b  = (const float*)d_in[10];
  const float* out_w  = (const float*)d_in[11];
  const float* out_b  = (const float*)d_in[12];
  float* out = (float*)d_out;

  // d_out = 384 u16-planes, scratch only BEFORE gemm_out:
  //   xp bf16: planes 0..191 ; t1 bf16: planes 192..239 (b0) / 288..335 (b1)
  u16* du16 = (u16*)d_out;

  // ws layout: y2, y1 each [2][48][Sn] bf16 = 50,331,648 B; xb [2][96][Sn] = 100,663,296 B
  char* ws = (char*)d_ws;
  u16*    y2    = (u16*)ws;                                     // [0, 50331648)
  u16*    y1    = (u16*)(ws + 50331648);                        // [50331648, 100663296)
  u16*    xb    = (u16*)(ws + 100663296);                       // [100663296, 201326592)
  float2* psum  = (float2*)(ws + 201326592);                    // 6,144 B
  u16*    W2pad = (u16*)(ws + 201326592 + 6144);                // 39,936 B
  u16*    W3pad = (u16*)(ws + 201326592 + 6144 + 39936);        // 19,968 B
  float*  bias2 = (float*)(ws + 201326592 + 6144 + 39936 + 19968); // 768 B

  // 1) norm stats + bf16 cast of x
  k_stats_partial<<<768, 256, 0, stream>>>(x, psum, xb);
  // 2) finalize + fold norm into in-proj (parallel); emit weight images
  k_fold<<<288, 96, 0, stream>>>(psum, gamma, beta, in_w, in_b, out_w, W2pad, W3pad, bias2);
  // 3) xp = W2*xb + bias2  (MFMA, bf16 into d_out planes 0..191)
  k_gemm<0><<<8192, 256, 0, stream>>>(xb, nullptr, nullptr, W2pad, bias2, du16, nullptr);
  // 4) merged: t1 = silu(dw_ssm(xp[:, :48])) -> planes 192.. ; y2 = silu(dw_sym(xp[:, 48:])) -> ws
  k_dws2<1,1><<<12288, 256, 0, stream>>>(du16, 96, 0, du16, 96, 192, y2, ssm_w, ssm_b, sym_w, sym_b);
  // 5) y1 = dw_mamba(t1) -> ws
  k_dws2<0,0><<<6144, 256, 0, stream>>>(du16, 96, 192, y1, 48, 0, nullptr, mam_w, mam_b, nullptr, nullptr);
  // 6) out = out_w * [y1; y2] + out_b + xb  (MFMA, fp32 into d_out; reads only ws)
  k_gemm<1><<<8192, 256, 0, stream>>>(xb, y1, y2, W3pad, out_b, nullptr, out);
}